// Round 1
// baseline (68.367 us; speedup 1.0000x reference)
//
#include <hip/hip_runtime.h>

#define EPS 0.1f
#define KSEL 16

typedef __attribute__((ext_vector_type(4))) float f32x4;
typedef __attribute__((ext_vector_type(8))) short s16x8;
typedef __attribute__((ext_vector_type(4))) short s16x4;

__device__ inline unsigned short f2bf(float f) {
    unsigned u = __float_as_uint(f);
    u = (u + 0x7FFFu + ((u >> 16) & 1u)) >> 16;   // RNE; inputs finite
    return (unsigned short)u;
}

// C[m][n] = sum_k Q[m][k] * Nb[n][k]   (A * B^T form)
// Writes dist = C, scor = 1 - C, and atomicMax of max(s^2, (s-1)^2) into maxws.
__global__ __launch_bounds__(256) void gemm_kernel(
    const float* __restrict__ Q, const float* __restrict__ Nb,
    float* __restrict__ dist, float* __restrict__ scor,
    float* __restrict__ maxws, int Mrows, int Nn, int Kd)
{
    // 128 rows x 64 bf16 = 128 bytes per row, XOR-swizzled (byte ^= (row&7)<<4)
    __shared__ __align__(16) char As[128 * 128];
    __shared__ __align__(16) char Bs[128 * 128];
    __shared__ float wmax[4];

    const int t = threadIdx.x;
    const int lane = t & 63;
    const int wave = t >> 6;
    const int wr = wave >> 1;          // 2x2 wave grid, each wave owns 64x64
    const int wc = wave & 1;
    const int brow = blockIdx.y * 128;
    const int bcol = blockIdx.x * 128;

    f32x4 acc[4][4] = {};

    const int nk = Kd >> 6;            // K-steps of 64
    for (int kt = 0; kt < nk; ++kt) {
        __syncthreads();
        // stage A tile (128 x 64 f32 -> bf16), reg-staged with conversion
        #pragma unroll
        for (int i = 0; i < 8; ++i) {
            int idx = i * 256 + t;         // float4 index, 2048 total
            int r = idx >> 4;              // row 0..127
            int c4 = idx & 15;             // float4 col
            const f32x4 a = *reinterpret_cast<const f32x4*>(
                &Q[(size_t)(brow + r) * Kd + kt * 64 + c4 * 4]);
            s16x4 p;
            p[0] = (short)f2bf(a[0]); p[1] = (short)f2bf(a[1]);
            p[2] = (short)f2bf(a[2]); p[3] = (short)f2bf(a[3]);
            int byte = (c4 * 8) ^ ((r & 7) << 4);
            *reinterpret_cast<s16x4*>(As + r * 128 + byte) = p;
        }
        // stage B tile from Nb rows (B^T layout: Bs[col][k])
        #pragma unroll
        for (int i = 0; i < 8; ++i) {
            int idx = i * 256 + t;
            int r = idx >> 4;
            int c4 = idx & 15;
            const f32x4 a = *reinterpret_cast<const f32x4*>(
                &Nb[(size_t)(bcol + r) * Kd + kt * 64 + c4 * 4]);
            s16x4 p;
            p[0] = (short)f2bf(a[0]); p[1] = (short)f2bf(a[1]);
            p[2] = (short)f2bf(a[2]); p[3] = (short)f2bf(a[3]);
            int byte = (c4 * 8) ^ ((r & 7) << 4);
            *reinterpret_cast<s16x4*>(Bs + r * 128 + byte) = p;
        }
        __syncthreads();
        // MFMA: 2 k-slices of 32
        #pragma unroll
        for (int ks = 0; ks < 2; ++ks) {
            s16x8 af[4], bfr[4];
            int kb = ks * 64 + ((lane >> 4) << 4);   // byte offset of this lane's 8 bf16
            #pragma unroll
            for (int m = 0; m < 4; ++m) {
                int r = wr * 64 + m * 16 + (lane & 15);
                af[m] = *reinterpret_cast<const s16x8*>(As + r * 128 + (kb ^ ((r & 7) << 4)));
            }
            #pragma unroll
            for (int n = 0; n < 4; ++n) {
                int r = wc * 64 + n * 16 + (lane & 15);
                bfr[n] = *reinterpret_cast<const s16x8*>(Bs + r * 128 + (kb ^ ((r & 7) << 4)));
            }
            #pragma unroll
            for (int m = 0; m < 4; ++m)
                #pragma unroll
                for (int n = 0; n < 4; ++n)
                    acc[m][n] = __builtin_amdgcn_mfma_f32_16x16x32_bf16(
                        af[m], bfr[n], acc[m][n], 0, 0, 0);
        }
    }

    // epilogue: C/D layout col = lane&15, row = (lane>>4)*4 + j  [m89-verified]
    float mx = 0.0f;
    #pragma unroll
    for (int m = 0; m < 4; ++m) {
        #pragma unroll
        for (int n = 0; n < 4; ++n) {
            #pragma unroll
            for (int j = 0; j < 4; ++j) {
                float v = acc[m][n][j];
                int row = brow + wr * 64 + m * 16 + ((lane >> 4) << 2) + j;
                int col = bcol + wc * 64 + n * 16 + (lane & 15);
                size_t o = (size_t)row * Nn + col;
                dist[o] = v;
                float s = 1.0f - v;
                scor[o] = s;
                float c = fmaxf(s * s, (s - 1.0f) * (s - 1.0f));
                mx = fmaxf(mx, c);
            }
        }
    }
    #pragma unroll
    for (int off = 32; off; off >>= 1) mx = fmaxf(mx, __shfl_xor(mx, off));
    if (lane == 0) wmax[wave] = mx;
    __syncthreads();
    if (t == 0) {
        float m2 = fmaxf(fmaxf(wmax[0], wmax[1]), fmaxf(wmax[2], wmax[3]));
        atomicMax(reinterpret_cast<int*>(maxws), __float_as_int(m2));  // vals >= 0
    }
}

// One block (256 threads) per query row. Solves the 2-column Sinkhorn fixed
// point: rho <- rho * (nu1/nu0) * W/(n-W),  W(rho) = sum_i 1/(1+rho*R_i),
// R_i = exp((2*s_i - 1)/(M*EPS)).  Output: top_k_i = 1/(1+rho*R_i), masked.
__global__ __launch_bounds__(256) void sinkhorn_kernel(
    const float* __restrict__ scor, float* __restrict__ out0,
    const float* __restrict__ maxws, int Nn)
{
    const int b = blockIdx.x;
    const int t = threadIdx.x;
    const int lane = t & 63;
    const int wave = t >> 6;
    __shared__ float sred[4];
    __shared__ float srho;

    const float Mmax = *maxws;
    const float invME = 1.0f / (Mmax * EPS);
    const float nuRatio = (float)(Nn - KSEL) / (float)KSEL;   // 255
    const float fn = (float)Nn;

    const float* row = scor + (size_t)b * Nn;
    float R[16];
    #pragma unroll
    for (int i = 0; i < 16; ++i) {
        float s = row[t + 256 * i];
        R[i] = __expf((2.0f * s - 1.0f) * invME);
    }

    float rho = 1.0f;   // g0 = g1 = 0 initial condition
    for (int it = 0; it < 12; ++it) {
        float w = 0.0f;
        #pragma unroll
        for (int i = 0; i < 16; ++i)
            w += __builtin_amdgcn_rcpf(fmaf(rho, R[i], 1.0f));
        #pragma unroll
        for (int off = 32; off; off >>= 1) w += __shfl_xor(w, off);
        if (lane == 0) sred[wave] = w;
        __syncthreads();
        if (t == 0) {
            float W = sred[0] + sred[1] + sred[2] + sred[3];
            srho = rho * nuRatio * W / (fn - W);
        }
        __syncthreads();
        rho = srho;
    }

    float* orow = out0 + (size_t)b * Nn;
    #pragma unroll
    for (int i = 0; i < 16; ++i) {
        float v = 1.0f / fmaf(rho, R[i], 1.0f);
        orow[t + 256 * i] = (v < 0.3f) ? 0.0f : v;
    }
}

extern "C" void kernel_launch(void* const* d_in, const int* in_sizes, int n_in,
                              void* d_out, int out_size, void* d_ws, size_t ws_size,
                              hipStream_t stream) {
    const float* Q  = (const float*)d_in[0];
    const float* Nb = (const float*)d_in[1];
    const int Kd = 256;
    const int Mrows = in_sizes[0] / Kd;   // 2048
    const int Nn    = in_sizes[1] / Kd;   // 4096

    float* out0 = (float*)d_out;                       // top_k_seq
    float* dist = out0 + (size_t)Mrows * Nn;           // distances
    float* scor = dist + (size_t)Mrows * Nn;           // scores
    float* maxws = (float*)d_ws;

    hipMemsetAsync(d_ws, 0, 4, stream);

    dim3 g1(Nn / 128, Mrows / 128);
    gemm_kernel<<<g1, 256, 0, stream>>>(Q, Nb, dist, scor, maxws, Mrows, Nn, Kd);
    sinkhorn_kernel<<<Mrows, 256, 0, stream>>>(scor, out0, maxws, Nn);
}

// Round 2
// 55.431 us; speedup vs baseline: 1.2334x; 1.2334x over previous
//
#include <hip/hip_runtime.h>

#define EPS 0.1f
#define KSEL 16

typedef __attribute__((ext_vector_type(4))) float f32x4;
typedef __attribute__((ext_vector_type(8))) short s16x8;
typedef __attribute__((ext_vector_type(4))) short s16x4;

__device__ inline unsigned short f2bf(float f) {
    unsigned u = __float_as_uint(f);
    u = (u + 0x7FFFu + ((u >> 16) & 1u)) >> 16;   // RNE; inputs finite
    return (unsigned short)u;
}

__device__ inline s16x4 cvt4(f32x4 a) {
    s16x4 p;
    p[0] = (short)f2bf(a[0]); p[1] = (short)f2bf(a[1]);
    p[2] = (short)f2bf(a[2]); p[3] = (short)f2bf(a[3]);
    return p;
}

// C[m][n] = sum_k Q[m][k]*Nb[n][k].  Block tile 128(M) x 64(N), BK=64,
// 512 threads = 8 waves in 4x2, each wave a 32x32 sub-tile.
// Double-buffered LDS, one barrier per K-step.
// Writes dist=C, scor=1-C, atomicMax of max(s^2,(s-1)^2) into maxws.
__global__ __launch_bounds__(512, 6) void gemm_kernel(
    const float* __restrict__ Q, const float* __restrict__ Nb,
    float* __restrict__ dist, float* __restrict__ scor,
    float* __restrict__ maxws, int Nn, int Kd)
{
    __shared__ __align__(16) char As[2][128 * 128];  // 128 rows x 64 bf16, swizzled
    __shared__ __align__(16) char Bs[2][64 * 128];   // 64 rows x 64 bf16, swizzled
    __shared__ float wmax[8];

    const int t = threadIdx.x;
    const int lane = t & 63;
    const int wave = t >> 6;
    const int wr = wave >> 1;          // 0..3
    const int wc = wave & 1;           // 0..1
    const int brow = blockIdx.y * 128;
    const int bcol = blockIdx.x * 64;

    f32x4 acc[2][2] = {};
    f32x4 pa[4], pb[2];

    const int nk = Kd >> 6;            // 4 K-steps of 64

    auto load_tiles = [&](int kt) {
        #pragma unroll
        for (int i = 0; i < 4; ++i) {
            int idx = i * 512 + t;         // A: 128 rows x 16 float4
            int r = idx >> 4, c4 = idx & 15;
            pa[i] = *reinterpret_cast<const f32x4*>(
                &Q[(size_t)(brow + r) * Kd + kt * 64 + c4 * 4]);
        }
        #pragma unroll
        for (int i = 0; i < 2; ++i) {
            int idx = i * 512 + t;         // B: 64 rows x 16 float4
            int r = idx >> 4, c4 = idx & 15;
            pb[i] = *reinterpret_cast<const f32x4*>(
                &Nb[(size_t)(bcol + r) * Kd + kt * 64 + c4 * 4]);
        }
    };
    auto write_tiles = [&](int buf) {
        #pragma unroll
        for (int i = 0; i < 4; ++i) {
            int idx = i * 512 + t;
            int r = idx >> 4, c4 = idx & 15;
            *reinterpret_cast<s16x4*>(&As[buf][r * 128 + ((c4 * 8) ^ ((r & 7) << 4))]) = cvt4(pa[i]);
        }
        #pragma unroll
        for (int i = 0; i < 2; ++i) {
            int idx = i * 512 + t;
            int r = idx >> 4, c4 = idx & 15;
            *reinterpret_cast<s16x4*>(&Bs[buf][r * 128 + ((c4 * 8) ^ ((r & 7) << 4))]) = cvt4(pb[i]);
        }
    };

    load_tiles(0);
    write_tiles(0);
    __syncthreads();
    int cur = 0;

    for (int kt = 0; kt < nk; ++kt) {
        if (kt + 1 < nk) load_tiles(kt + 1);   // issue next-tile loads early
        #pragma unroll
        for (int ks = 0; ks < 2; ++ks) {
            int kb = ks * 64 + ((lane >> 4) << 4);
            s16x8 af[2], bfr[2];
            #pragma unroll
            for (int m = 0; m < 2; ++m) {
                int r = wr * 32 + m * 16 + (lane & 15);
                af[m] = *reinterpret_cast<const s16x8*>(
                    &As[cur][r * 128 + (kb ^ ((r & 7) << 4))]);
            }
            #pragma unroll
            for (int n = 0; n < 2; ++n) {
                int r = wc * 32 + n * 16 + (lane & 15);
                bfr[n] = *reinterpret_cast<const s16x8*>(
                    &Bs[cur][r * 128 + (kb ^ ((r & 7) << 4))]);
            }
            #pragma unroll
            for (int m = 0; m < 2; ++m)
                #pragma unroll
                for (int n = 0; n < 2; ++n)
                    acc[m][n] = __builtin_amdgcn_mfma_f32_16x16x32_bf16(
                        af[m], bfr[n], acc[m][n], 0, 0, 0);
        }
        if (kt + 1 < nk) {
            write_tiles(cur ^ 1);    // other buffer: last read before prev barrier
            __syncthreads();
            cur ^= 1;
        }
    }

    // epilogue: C/D layout col = lane&15, row = (lane>>4)*4 + j
    float mx = 0.0f;
    #pragma unroll
    for (int m = 0; m < 2; ++m) {
        #pragma unroll
        for (int n = 0; n < 2; ++n) {
            #pragma unroll
            for (int j = 0; j < 4; ++j) {
                float v = acc[m][n][j];
                int row = brow + wr * 32 + m * 16 + ((lane >> 4) << 2) + j;
                int col = bcol + wc * 32 + n * 16 + (lane & 15);
                size_t o = (size_t)row * Nn + col;
                dist[o] = v;
                float s = 1.0f - v;
                scor[o] = s;
                mx = fmaxf(mx, fmaxf(s * s, (s - 1.0f) * (s - 1.0f)));
            }
        }
    }
    #pragma unroll
    for (int off = 32; off; off >>= 1) mx = fmaxf(mx, __shfl_xor(mx, off));
    if (lane == 0) wmax[wave] = mx;
    __syncthreads();
    if (t == 0) {
        float m2 = wmax[0];
        #pragma unroll
        for (int w = 1; w < 8; ++w) m2 = fmaxf(m2, wmax[w]);
        atomicMax(reinterpret_cast<int*>(maxws), __float_as_int(m2));  // vals >= 0
    }
}

// One block (256 threads) per query row. 2-column Sinkhorn fixed point:
// rho <- rho*(nu1/nu0)*W/(n-W),  W(rho)=sum_i 1/(1+rho*R_i),
// R_i = exp((2*s_i-1)/(M*EPS)).  Output: top_k_i = 1/(1+rho*R_i), masked.
__global__ __launch_bounds__(256) void sinkhorn_kernel(
    const float* __restrict__ scor, float* __restrict__ out0,
    const float* __restrict__ maxws, int Nn)
{
    const int b = blockIdx.x;
    const int t = threadIdx.x;
    const int lane = t & 63;
    const int wave = t >> 6;
    __shared__ float sred[4];
    __shared__ float srho;

    const float Mmax = *maxws;
    const float invME = 1.0f / (Mmax * EPS);
    const float nuRatio = (float)(Nn - KSEL) / (float)KSEL;
    const float fn = (float)Nn;

    const float* row = scor + (size_t)b * Nn;
    float R[16];
    #pragma unroll
    for (int i = 0; i < 4; ++i) {
        f32x4 s4 = *reinterpret_cast<const f32x4*>(&row[(i * 256 + t) * 4]);
        #pragma unroll
        for (int j = 0; j < 4; ++j)
            R[i * 4 + j] = __expf((2.0f * s4[j] - 1.0f) * invME);
    }

    float rho = 1.0f;   // g0 = g1 = 0 initial condition
    for (int it = 0; it < 12; ++it) {
        float w = 0.0f;
        #pragma unroll
        for (int i = 0; i < 16; ++i)
            w += __builtin_amdgcn_rcpf(fmaf(rho, R[i], 1.0f));
        #pragma unroll
        for (int off = 32; off; off >>= 1) w += __shfl_xor(w, off);
        if (lane == 0) sred[wave] = w;
        __syncthreads();
        if (t == 0) {
            float W = sred[0] + sred[1] + sred[2] + sred[3];
            srho = rho * nuRatio * W / (fn - W);
        }
        __syncthreads();
        rho = srho;
    }

    float* orow = out0 + (size_t)b * Nn;
    #pragma unroll
    for (int i = 0; i < 4; ++i) {
        f32x4 v4;
        #pragma unroll
        for (int j = 0; j < 4; ++j) {
            float v = 1.0f / fmaf(rho, R[i * 4 + j], 1.0f);
            v4[j] = (v < 0.3f) ? 0.0f : v;
        }
        *reinterpret_cast<f32x4*>(&orow[(i * 256 + t) * 4]) = v4;
    }
}

extern "C" void kernel_launch(void* const* d_in, const int* in_sizes, int n_in,
                              void* d_out, int out_size, void* d_ws, size_t ws_size,
                              hipStream_t stream) {
    const float* Q  = (const float*)d_in[0];
    const float* Nb = (const float*)d_in[1];
    const int Kd = 256;
    const int Mrows = in_sizes[0] / Kd;   // 2048
    const int Nn    = in_sizes[1] / Kd;   // 4096

    float* out0 = (float*)d_out;                       // top_k_seq
    float* dist = out0 + (size_t)Mrows * Nn;           // distances
    float* scor = dist + (size_t)Mrows * Nn;           // scores
    float* maxws = (float*)d_ws;

    hipMemsetAsync(d_ws, 0, 4, stream);

    dim3 g1(Nn / 64, Mrows / 128);
    gemm_kernel<<<g1, 512, 0, stream>>>(Q, Nb, dist, scor, maxws, Nn, Kd);
    sinkhorn_kernel<<<Mrows, 256, 0, stream>>>(scor, out0, maxws, Nn);
}

// Round 3
// 51.484 us; speedup vs baseline: 1.3279x; 1.0767x over previous
//
#include <hip/hip_runtime.h>
#include <hip/hip_bf16.h>

#define EPS 0.1f
#define KSEL 16

typedef __attribute__((ext_vector_type(4))) float f32x4;
typedef __attribute__((ext_vector_type(8))) short s16x8;
typedef __attribute__((ext_vector_type(4))) short s16x4;

__device__ inline s16x4 cvt4(f32x4 a) {
    // scalar casts -> compiler packs v_cvt_pk_bf16_f32 (m240: don't hand-write)
    s16x4 p;
    p[0] = __builtin_bit_cast(short, __float2bfloat16(a[0]));
    p[1] = __builtin_bit_cast(short, __float2bfloat16(a[1]));
    p[2] = __builtin_bit_cast(short, __float2bfloat16(a[2]));
    p[3] = __builtin_bit_cast(short, __float2bfloat16(a[3]));
    return p;
}

// C[m][n] = sum_k Q[m][k]*Nb[n][k].  Block tile 128(M) x 64(N), BK=64,
// 512 threads = 8 waves in 4x2, each wave a 32x32 sub-tile.
// Double-buffered LDS, one barrier per K-step.
// Epilogue: C -> LDS (reuse A buffers) -> f32x4 stores of dist and scor=1-C.
// Per-block max of max(s^2,(s-1)^2) -> bmax[bid]  (no atomics, no memset).
__global__ __launch_bounds__(512, 6) void gemm_kernel(
    const float* __restrict__ Q, const float* __restrict__ Nb,
    float* __restrict__ dist, float* __restrict__ scor,
    float* __restrict__ bmax, int Nn, int Kd)
{
    __shared__ __align__(16) char As[2][128 * 128];  // 128 rows x 64 bf16, swizzled
    __shared__ __align__(16) char Bs[2][64 * 128];   // 64 rows x 64 bf16, swizzled
    __shared__ float wmax[8];

    const int t = threadIdx.x;
    const int lane = t & 63;
    const int wave = t >> 6;
    const int wr = wave >> 1;          // 0..3
    const int wc = wave & 1;           // 0..1
    const int brow = blockIdx.y * 128;
    const int bcol = blockIdx.x * 64;

    f32x4 acc[2][2] = {};
    f32x4 pa[4], pb[2];

    const int nk = Kd >> 6;            // 4 K-steps of 64

    auto load_tiles = [&](int kt) {
        #pragma unroll
        for (int i = 0; i < 4; ++i) {
            int idx = i * 512 + t;         // A: 128 rows x 16 float4
            int r = idx >> 4, c4 = idx & 15;
            pa[i] = *reinterpret_cast<const f32x4*>(
                &Q[(size_t)(brow + r) * Kd + kt * 64 + c4 * 4]);
        }
        #pragma unroll
        for (int i = 0; i < 2; ++i) {
            int idx = i * 512 + t;         // B: 64 rows x 16 float4
            int r = idx >> 4, c4 = idx & 15;
            pb[i] = *reinterpret_cast<const f32x4*>(
                &Nb[(size_t)(bcol + r) * Kd + kt * 64 + c4 * 4]);
        }
    };
    auto write_tiles = [&](int buf) {
        #pragma unroll
        for (int i = 0; i < 4; ++i) {
            int idx = i * 512 + t;
            int r = idx >> 4, c4 = idx & 15;
            *reinterpret_cast<s16x4*>(&As[buf][r * 128 + ((c4 * 8) ^ ((r & 7) << 4))]) = cvt4(pa[i]);
        }
        #pragma unroll
        for (int i = 0; i < 2; ++i) {
            int idx = i * 512 + t;
            int r = idx >> 4, c4 = idx & 15;
            *reinterpret_cast<s16x4*>(&Bs[buf][r * 128 + ((c4 * 8) ^ ((r & 7) << 4))]) = cvt4(pb[i]);
        }
    };

    load_tiles(0);
    write_tiles(0);
    __syncthreads();
    int cur = 0;

    for (int kt = 0; kt < nk; ++kt) {
        if (kt + 1 < nk) load_tiles(kt + 1);   // issue next-tile loads early
        #pragma unroll
        for (int ks = 0; ks < 2; ++ks) {
            int kb = ks * 64 + ((lane >> 4) << 4);
            s16x8 af[2], bfr[2];
            #pragma unroll
            for (int m = 0; m < 2; ++m) {
                int r = wr * 32 + m * 16 + (lane & 15);
                af[m] = *reinterpret_cast<const s16x8*>(
                    &As[cur][r * 128 + (kb ^ ((r & 7) << 4))]);
            }
            #pragma unroll
            for (int n = 0; n < 2; ++n) {
                int r = wc * 32 + n * 16 + (lane & 15);
                bfr[n] = *reinterpret_cast<const s16x8*>(
                    &Bs[cur][r * 128 + (kb ^ ((r & 7) << 4))]);
            }
            #pragma unroll
            for (int m = 0; m < 2; ++m)
                #pragma unroll
                for (int n = 0; n < 2; ++n)
                    acc[m][n] = __builtin_amdgcn_mfma_f32_16x16x32_bf16(
                        af[m], bfr[n], acc[m][n], 0, 0, 0);
        }
        if (kt + 1 < nk) {
            write_tiles(cur ^ 1);    // other buffer: last read before prev barrier
            __syncthreads();
            cur ^= 1;
        }
    }

    // ---- epilogue: transpose C through LDS (A buffers are dead: 32 KB) ----
    __syncthreads();   // all MFMA LDS reads complete before overwrite
    float* Ct = reinterpret_cast<float*>(&As[0][0]);   // [128][64] f32
    #pragma unroll
    for (int m = 0; m < 2; ++m)
        #pragma unroll
        for (int n = 0; n < 2; ++n)
            #pragma unroll
            for (int j = 0; j < 4; ++j) {
                int row = wr * 32 + m * 16 + ((lane >> 4) << 2) + j;
                int col = wc * 32 + n * 16 + (lane & 15);
                Ct[row * 64 + col] = acc[m][n][j];   // 2-way bank alias: free
            }
    __syncthreads();

    float mx = 0.0f;
    #pragma unroll
    for (int it = 0; it < 4; ++it) {
        int r = wave * 16 + it * 4 + (lane >> 4);
        int c = (lane & 15) * 4;
        f32x4 v = *reinterpret_cast<f32x4*>(&Ct[r * 64 + c]);
        f32x4 s4;
        #pragma unroll
        for (int j = 0; j < 4; ++j) {
            float s = 1.0f - v[j];
            s4[j] = s;
            mx = fmaxf(mx, fmaxf(s * s, (s - 1.0f) * (s - 1.0f)));
        }
        size_t o = (size_t)(brow + r) * Nn + bcol + c;
        *reinterpret_cast<f32x4*>(&dist[o]) = v;    // wave: 4 x 256B contiguous
        *reinterpret_cast<f32x4*>(&scor[o]) = s4;
    }

    #pragma unroll
    for (int off = 32; off; off >>= 1) mx = fmaxf(mx, __shfl_xor(mx, off));
    if (lane == 0) wmax[wave] = mx;
    __syncthreads();
    if (t == 0) {
        float m2 = wmax[0];
        #pragma unroll
        for (int w = 1; w < 8; ++w) m2 = fmaxf(m2, wmax[w]);
        bmax[blockIdx.y * gridDim.x + blockIdx.x] = m2;
    }
}

// One block (256 threads) per query row. 2-column Sinkhorn fixed point:
// rho <- rho*(nu1/nu0)*W/(n-W),  W(rho)=sum_i 1/(1+rho*R_i),
// R_i = exp((2*s_i-1)/(M*EPS)).  Output: top_k_i = 1/(1+rho*R_i), masked.
// First reduces the 1024 per-block maxima to get M = C.max.
__global__ __launch_bounds__(256) void sinkhorn_kernel(
    const float* __restrict__ scor, float* __restrict__ out0,
    const float* __restrict__ bmax, int Nn, int nBmax)
{
    const int b = blockIdx.x;
    const int t = threadIdx.x;
    const int lane = t & 63;
    const int wave = t >> 6;
    __shared__ float sred[4];
    __shared__ float srho;
    __shared__ float sM;

    // global C.max from per-block maxima (nBmax = 1024, L2-resident)
    float m = 0.0f;
    for (int i = t; i < nBmax; i += 256) m = fmaxf(m, bmax[i]);
    #pragma unroll
    for (int off = 32; off; off >>= 1) m = fmaxf(m, __shfl_xor(m, off));
    if (lane == 0) sred[wave] = m;
    __syncthreads();
    if (t == 0) sM = fmaxf(fmaxf(sred[0], sred[1]), fmaxf(sred[2], sred[3]));
    __syncthreads();
    const float Mmax = sM;

    const float invME = 1.0f / (Mmax * EPS);
    const float nuRatio = (float)(Nn - KSEL) / (float)KSEL;
    const float fn = (float)Nn;

    const float* row = scor + (size_t)b * Nn;
    float R[16];
    #pragma unroll
    for (int i = 0; i < 4; ++i) {
        f32x4 s4 = *reinterpret_cast<const f32x4*>(&row[(i * 256 + t) * 4]);
        #pragma unroll
        for (int j = 0; j < 4; ++j)
            R[i * 4 + j] = __expf((2.0f * s4[j] - 1.0f) * invME);
    }

    float rho = 1.0f;   // g0 = g1 = 0 initial condition
    for (int it = 0; it < 12; ++it) {
        float w = 0.0f;
        #pragma unroll
        for (int i = 0; i < 16; ++i)
            w += __builtin_amdgcn_rcpf(fmaf(rho, R[i], 1.0f));
        #pragma unroll
        for (int off = 32; off; off >>= 1) w += __shfl_xor(w, off);
        if (lane == 0) sred[wave] = w;
        __syncthreads();
        if (t == 0) {
            float W = sred[0] + sred[1] + sred[2] + sred[3];
            srho = rho * nuRatio * W / (fn - W);
        }
        __syncthreads();
        rho = srho;
    }

    float* orow = out0 + (size_t)b * Nn;
    #pragma unroll
    for (int i = 0; i < 4; ++i) {
        f32x4 v4;
        #pragma unroll
        for (int j = 0; j < 4; ++j) {
            float v = 1.0f / fmaf(rho, R[i * 4 + j], 1.0f);
            v4[j] = (v < 0.3f) ? 0.0f : v;
        }
        *reinterpret_cast<f32x4*>(&orow[(i * 256 + t) * 4]) = v4;
    }
}

extern "C" void kernel_launch(void* const* d_in, const int* in_sizes, int n_in,
                              void* d_out, int out_size, void* d_ws, size_t ws_size,
                              hipStream_t stream) {
    const float* Q  = (const float*)d_in[0];
    const float* Nb = (const float*)d_in[1];
    const int Kd = 256;
    const int Mrows = in_sizes[0] / Kd;   // 2048
    const int Nn    = in_sizes[1] / Kd;   // 4096

    float* out0 = (float*)d_out;                       // top_k_seq
    float* dist = out0 + (size_t)Mrows * Nn;           // distances
    float* scor = dist + (size_t)Mrows * Nn;           // scores
    float* bmax = (float*)d_ws;                        // per-block maxima

    dim3 g1(Nn / 64, Mrows / 128);                     // 64 x 16 = 1024 blocks
    gemm_kernel<<<g1, 512, 0, stream>>>(Q, Nb, dist, scor, bmax, Nn, Kd);
    sinkhorn_kernel<<<Mrows, 256, 0, stream>>>(scor, out0, bmax, Nn,
                                               g1.x * g1.y);
}

// Round 5
// 48.308 us; speedup vs baseline: 1.4152x; 1.0657x over previous
//
#include <hip/hip_runtime.h>
#include <hip/hip_bf16.h>

#define EPS 0.1f
#define KSEL 16
#define KD 256

typedef __attribute__((ext_vector_type(4))) float f32x4;
typedef __attribute__((ext_vector_type(8))) short s16x8;
typedef __attribute__((ext_vector_type(4))) short s16x4;

__device__ inline s16x4 cvt4(f32x4 a) {
    // scalar casts -> compiler packs v_cvt_pk_bf16_f32 (m240: don't hand-write)
    s16x4 p;
    p[0] = __builtin_bit_cast(short, __float2bfloat16(a[0]));
    p[1] = __builtin_bit_cast(short, __float2bfloat16(a[1]));
    p[2] = __builtin_bit_cast(short, __float2bfloat16(a[2]));
    p[3] = __builtin_bit_cast(short, __float2bfloat16(a[3]));
    return p;
}

// C[m][n] = sum_k Q[m][k]*Nb[n][k].  Block tile 128(M) x 64(N), BK=64, nk=4.
// 512 threads = 8 waves (4x2), each wave a 32x32 sub-tile.
// Depth-2 REGISTER prefetch (tiles k and k+1 in flight) + double-buffered LDS.
// Epilogue: C -> LDS (reuse full As array, 32 KB) -> f32x4 stores.
// Per-block max of max(s^2,(s-1)^2) -> bmax[bid].
struct PF { f32x4 a[4]; f32x4 b[2]; };   // 6 x f32x4 = 24 VGPR per set

__global__ __launch_bounds__(512, 4) void gemm_kernel(
    const float* __restrict__ Q, const float* __restrict__ Nb,
    float* __restrict__ dist, float* __restrict__ scor,
    float* __restrict__ bmax, int Nn)
{
    __shared__ __align__(16) char As[2][128 * 128];  // 128 rows x 64 bf16, swizzled
    __shared__ __align__(16) char Bs[2][64 * 128];   // 64 rows x 64 bf16, swizzled
    __shared__ float wmax[8];

    const int t = threadIdx.x;
    const int lane = t & 63;
    const int wave = t >> 6;
    const int wr = wave >> 1;          // 0..3
    const int wc = wave & 1;           // 0..1
    const int brow = blockIdx.y * 128;
    const int bcol = blockIdx.x * 64;

    f32x4 acc[2][2] = {};
    PF R0, R1;

    // slot map: A has 128 rows x 8 col-pairs(32B) = 1024 slots (t and t+512);
    // B has 64 rows x 8 pairs = 512 slots (t).  Each slot = 2 contiguous f32x4.
    const int ra0 = t >> 3, pa0 = t & 7;            // A slot 0 (rows 0..63)
    const int ra1 = (512 + t) >> 3, pa1 = t & 7;    // A slot 1 (rows 64..127)
    const int rb  = t >> 3, pb = t & 7;             // B slot

    auto issue = [&](PF& R, int kt) {
        const float* qa0 = &Q[(size_t)(brow + ra0) * KD + kt * 64 + pa0 * 8];
        R.a[0] = *reinterpret_cast<const f32x4*>(qa0);
        R.a[1] = *reinterpret_cast<const f32x4*>(qa0 + 4);
        const float* qa1 = &Q[(size_t)(brow + ra1) * KD + kt * 64 + pa1 * 8];
        R.a[2] = *reinterpret_cast<const f32x4*>(qa1);
        R.a[3] = *reinterpret_cast<const f32x4*>(qa1 + 4);
        const float* qb = &Nb[(size_t)(bcol + rb) * KD + kt * 64 + pb * 8];
        R.b[0] = *reinterpret_cast<const f32x4*>(qb);
        R.b[1] = *reinterpret_cast<const f32x4*>(qb + 4);
    };
    auto commit = [&](PF& R, int buf) {
        s16x8 v;
        s16x4 lo = cvt4(R.a[0]), hi = cvt4(R.a[1]);
        #pragma unroll
        for (int j = 0; j < 4; ++j) { v[j] = lo[j]; v[4 + j] = hi[j]; }
        *reinterpret_cast<s16x8*>(&As[buf][ra0 * 128 + ((pa0 * 16) ^ ((ra0 & 7) << 4))]) = v;
        lo = cvt4(R.a[2]); hi = cvt4(R.a[3]);
        #pragma unroll
        for (int j = 0; j < 4; ++j) { v[j] = lo[j]; v[4 + j] = hi[j]; }
        *reinterpret_cast<s16x8*>(&As[buf][ra1 * 128 + ((pa1 * 16) ^ ((ra1 & 7) << 4))]) = v;
        lo = cvt4(R.b[0]); hi = cvt4(R.b[1]);
        #pragma unroll
        for (int j = 0; j < 4; ++j) { v[j] = lo[j]; v[4 + j] = hi[j]; }
        *reinterpret_cast<s16x8*>(&Bs[buf][rb * 128 + ((pb * 16) ^ ((rb & 7) << 4))]) = v;
    };
    auto mfma_step = [&](int buf) {
        #pragma unroll
        for (int ks = 0; ks < 2; ++ks) {
            int kb = ks * 64 + ((lane >> 4) << 4);
            s16x8 af[2], bf[2];
            #pragma unroll
            for (int m = 0; m < 2; ++m) {
                int r = wr * 32 + m * 16 + (lane & 15);
                af[m] = *reinterpret_cast<const s16x8*>(
                    &As[buf][r * 128 + (kb ^ ((r & 7) << 4))]);
            }
            #pragma unroll
            for (int n = 0; n < 2; ++n) {
                int r = wc * 32 + n * 16 + (lane & 15);
                bf[n] = *reinterpret_cast<const s16x8*>(
                    &Bs[buf][r * 128 + (kb ^ ((r & 7) << 4))]);
            }
            #pragma unroll
            for (int m = 0; m < 2; ++m)
                #pragma unroll
                for (int n = 0; n < 2; ++n)
                    acc[m][n] = __builtin_amdgcn_mfma_f32_16x16x32_bf16(
                        af[m], bf[n], acc[m][n], 0, 0, 0);
        }
    };

    // ---- pipeline: nk = 4 fixed (KD=256, BK=64) ----
    issue(R0, 0);
    issue(R1, 1);
    commit(R0, 0);            // waits R0 only (R1 stays in flight)
    __syncthreads();

    issue(R0, 2);             // in flight across step 0
    mfma_step(0);
    commit(R1, 1);            // waits R1 (older than R0's new loads)
    __syncthreads();

    issue(R1, 3);             // in flight across step 1
    mfma_step(1);
    commit(R0, 0);
    __syncthreads();

    mfma_step(0);
    commit(R1, 1);
    __syncthreads();

    mfma_step(1);
    __syncthreads();   // REQUIRED: Ct spans As[0]+As[1]; all waves must finish
                       // their As[1]/Bs[1] fragment reads before overwrite.

    // ---- epilogue: transpose C through As (32 KB dead after barrier) ----
    float* Ct = reinterpret_cast<float*>(&As[0][0]);   // [128][64] f32
    #pragma unroll
    for (int m = 0; m < 2; ++m)
        #pragma unroll
        for (int n = 0; n < 2; ++n)
            #pragma unroll
            for (int j = 0; j < 4; ++j) {
                int row = wr * 32 + m * 16 + ((lane >> 4) << 2) + j;
                int col = wc * 32 + n * 16 + (lane & 15);
                Ct[row * 64 + col] = acc[m][n][j];   // 2-way bank alias: free
            }
    __syncthreads();

    float mx = 0.0f;
    #pragma unroll
    for (int it = 0; it < 4; ++it) {
        int r = wave * 16 + it * 4 + (lane >> 4);
        int c = (lane & 15) * 4;
        f32x4 v = *reinterpret_cast<f32x4*>(&Ct[r * 64 + c]);
        f32x4 s4;
        #pragma unroll
        for (int j = 0; j < 4; ++j) {
            float s = 1.0f - v[j];
            s4[j] = s;
            mx = fmaxf(mx, fmaxf(s * s, (s - 1.0f) * (s - 1.0f)));
        }
        size_t o = (size_t)(brow + r) * Nn + bcol + c;
        *reinterpret_cast<f32x4*>(&dist[o]) = v;    // wave: 4 x 256B contiguous
        *reinterpret_cast<f32x4*>(&scor[o]) = s4;
    }

    #pragma unroll
    for (int off = 32; off; off >>= 1) mx = fmaxf(mx, __shfl_xor(mx, off));
    if (lane == 0) wmax[wave] = mx;
    __syncthreads();
    if (t == 0) {
        float m2 = wmax[0];
        #pragma unroll
        for (int w = 1; w < 8; ++w) m2 = fmaxf(m2, wmax[w]);
        bmax[blockIdx.y * gridDim.x + blockIdx.x] = m2;
    }
}

// One block (256 threads) per query row. 2-column Sinkhorn fixed point:
// rho <- rho*(nu1/nu0)*W/(n-W),  W(rho)=sum_i 1/(1+rho*R_i),
// R_i = exp((2*s_i-1)/(M*EPS)).  Output: top_k_i = 1/(1+rho*R_i), masked.
// First reduces the 1024 per-block maxima to get M = C.max.
__global__ __launch_bounds__(256) void sinkhorn_kernel(
    const float* __restrict__ scor, float* __restrict__ out0,
    const float* __restrict__ bmax, int Nn, int nBmax)
{
    const int b = blockIdx.x;
    const int t = threadIdx.x;
    const int lane = t & 63;
    const int wave = t >> 6;
    __shared__ float sred[4];
    __shared__ float srho;
    __shared__ float sM;

    // global C.max from per-block maxima (nBmax = 1024, L2-resident)
    float m = 0.0f;
    for (int i = t; i < nBmax; i += 256) m = fmaxf(m, bmax[i]);
    #pragma unroll
    for (int off = 32; off; off >>= 1) m = fmaxf(m, __shfl_xor(m, off));
    if (lane == 0) sred[wave] = m;
    __syncthreads();
    if (t == 0) sM = fmaxf(fmaxf(sred[0], sred[1]), fmaxf(sred[2], sred[3]));
    __syncthreads();
    const float Mmax = sM;

    const float invME = 1.0f / (Mmax * EPS);
    const float nuRatio = (float)(Nn - KSEL) / (float)KSEL;
    const float fn = (float)Nn;

    const float* row = scor + (size_t)b * Nn;
    float R[16];
    #pragma unroll
    for (int i = 0; i < 4; ++i) {
        f32x4 s4 = *reinterpret_cast<const f32x4*>(&row[(i * 256 + t) * 4]);
        #pragma unroll
        for (int j = 0; j < 4; ++j)
            R[i * 4 + j] = __expf((2.0f * s4[j] - 1.0f) * invME);
    }

    float rho = 1.0f;   // g0 = g1 = 0 initial condition
    for (int it = 0; it < 12; ++it) {
        float w = 0.0f;
        #pragma unroll
        for (int i = 0; i < 16; ++i)
            w += __builtin_amdgcn_rcpf(fmaf(rho, R[i], 1.0f));
        #pragma unroll
        for (int off = 32; off; off >>= 1) w += __shfl_xor(w, off);
        if (lane == 0) sred[wave] = w;
        __syncthreads();
        if (t == 0) {
            float W = sred[0] + sred[1] + sred[2] + sred[3];
            srho = rho * nuRatio * W / (fn - W);
        }
        __syncthreads();
        rho = srho;
    }

    float* orow = out0 + (size_t)b * Nn;
    #pragma unroll
    for (int i = 0; i < 4; ++i) {
        f32x4 v4;
        #pragma unroll
        for (int j = 0; j < 4; ++j) {
            float v = 1.0f / fmaf(rho, R[i * 4 + j], 1.0f);
            v4[j] = (v < 0.3f) ? 0.0f : v;
        }
        *reinterpret_cast<f32x4*>(&orow[(i * 256 + t) * 4]) = v4;
    }
}

extern "C" void kernel_launch(void* const* d_in, const int* in_sizes, int n_in,
                              void* d_out, int out_size, void* d_ws, size_t ws_size,
                              hipStream_t stream) {
    const float* Q  = (const float*)d_in[0];
    const float* Nb = (const float*)d_in[1];
    const int Mrows = in_sizes[0] / KD;   // 2048
    const int Nn    = in_sizes[1] / KD;   // 4096

    float* out0 = (float*)d_out;                       // top_k_seq
    float* dist = out0 + (size_t)Mrows * Nn;           // distances
    float* scor = dist + (size_t)Mrows * Nn;           // scores
    float* bmax = (float*)d_ws;                        // per-block maxima

    dim3 g1(Nn / 64, Mrows / 128);                     // 64 x 16 = 1024 blocks
    gemm_kernel<<<g1, 512, 0, stream>>>(Q, Nb, dist, scor, bmax, Nn);
    sinkhorn_kernel<<<Mrows, 256, 0, stream>>>(scor, out0, bmax, Nn,
                                               g1.x * g1.y);
}